// Round 2
// baseline (2228.109 us; speedup 1.0000x reference)
//
#include <hip/hip_runtime.h>
#include <cstdint>
#include <cmath>

// RNN: out[t,b,h] = tanh(x[b,t,:]@Wx + bx + h_{t-1}@Wh + bh), h_0 = h0.
// Sizes fixed by the problem:
#define BB 128
#define LL 1024
#define II 256
#define HH 512

typedef _Float16 f16;
typedef _Float16 f16x2 __attribute__((ext_vector_type(2)));
typedef _Float16 f16x4 __attribute__((ext_vector_type(4)));
typedef _Float16 f16x8 __attribute__((ext_vector_type(8)));
typedef float f32x4 __attribute__((ext_vector_type(4)));

// ---------------- Phase 1: xp[t,b,:] = x[b,t,:] @ Wx + bx  (written to out) --
// f16 MFMA GEMM. Block tile: (one t) x (all 128 b) x (128 cols). 4 waves 2x2,
// each wave 64x64 out = 4x4 frags of 16x16, K staged in LDS with BK=64.
__global__ __launch_bounds__(256, 4) void xproj_gemm(
    const float* __restrict__ x, const float* __restrict__ Wx,
    const float* __restrict__ bx, float* __restrict__ out) {
  const int t0 = blockIdx.x;        // time index
  const int n0 = blockIdx.y * 128;  // output-column tile
  __shared__ f16 As[128][72];       // [b][k], pitch 72 keeps b128 reads aligned
  __shared__ f16 Bs[128][72];       // TRANSPOSED: [col][k]
  const int tid  = threadIdx.x;
  const int lane = tid & 63;
  const int wid  = tid >> 6;
  const int wr   = wid >> 1, wc = wid & 1;

  f32x4 acc[4][4];
#pragma unroll
  for (int mi = 0; mi < 4; ++mi)
#pragma unroll
    for (int ni = 0; ni < 4; ++ni) acc[mi][ni] = f32x4{0.f, 0.f, 0.f, 0.f};

  for (int kt = 0; kt < 4; ++kt) {
    const int k0 = kt * 64;
    // Stage A: x[b, t0, k0..k0+63] -> As[b][0..63], float4 loads, f16 stores.
#pragma unroll
    for (int rep = 0; rep < 8; ++rep) {
      const int idx = rep * 256 + tid;   // float4 index, 2048 total
      const int row = idx >> 4;          // 16 float4 per row
      const int c4  = idx & 15;
      const float4 v =
          *(reinterpret_cast<const float4*>(x + ((size_t)row * LL + t0) * II + k0) + c4);
      f16x4 p = {(f16)v.x, (f16)v.y, (f16)v.z, (f16)v.w};
      *reinterpret_cast<f16x4*>(&As[row][c4 * 4]) = p;
    }
    // Stage B transposed: Wx[k0+k][n0+c] -> Bs[c][k]. Thread owns one column
    // half: contiguous f16x8 stores (no scatter-write conflicts).
    {
      const int c  = tid & 127;
      const int kh = tid >> 7;  // 0..1 (k-halves of 32)
      const float* wp = Wx + (size_t)(k0 + kh * 32) * HH + n0 + c;
#pragma unroll
      for (int m8 = 0; m8 < 4; ++m8) {
        f16x8 pk;
#pragma unroll
        for (int j = 0; j < 8; ++j) pk[j] = (f16)wp[(size_t)(m8 * 8 + j) * HH];
        *reinterpret_cast<f16x8*>(&Bs[c][kh * 32 + m8 * 8]) = pk;
      }
    }
    __syncthreads();
#pragma unroll
    for (int kk2 = 0; kk2 < 2; ++kk2) {
      const int kf = kk2 * 32 + ((lane >> 4) << 3);
      f16x8 af[4], bf[4];
#pragma unroll
      for (int mi = 0; mi < 4; ++mi)
        af[mi] = *reinterpret_cast<const f16x8*>(&As[wr * 64 + mi * 16 + (lane & 15)][kf]);
#pragma unroll
      for (int ni = 0; ni < 4; ++ni)
        bf[ni] = *reinterpret_cast<const f16x8*>(&Bs[wc * 64 + ni * 16 + (lane & 15)][kf]);
#pragma unroll
      for (int mi = 0; mi < 4; ++mi)
#pragma unroll
        for (int ni = 0; ni < 4; ++ni)
          acc[mi][ni] =
              __builtin_amdgcn_mfma_f32_16x16x32_f16(af[mi], bf[ni], acc[mi][ni], 0, 0, 0);
    }
    __syncthreads();
  }
  // Epilogue: C/D layout col=lane&15, row=(lane>>4)*4+q. Block's row == b.
#pragma unroll
  for (int mi = 0; mi < 4; ++mi) {
    const int row = wr * 64 + mi * 16 + ((lane >> 4) << 2);
#pragma unroll
    for (int ni = 0; ni < 4; ++ni) {
      const int col = n0 + wc * 64 + ni * 16 + (lane & 15);
      const float bxi = bx[col];
#pragma unroll
      for (int q = 0; q < 4; ++q)
        out[((size_t)t0 * BB + (row + q)) * HH + col] = acc[mi][ni][q] + bxi;
    }
  }
}

// ---------------- Phase 2: persistent per-row scan ---------------------------
// 128 blocks (one batch row per CU), 1024 threads. Wh held f16-packed on-CU:
// 96 pk-dwords/thread in VGPRs (384 KB) + 32 pk-dwords/thread in LDS (128 KB,
// XOR-swizzled so b128 reads hit LDS BW floor). h broadcast via LDS, f32
// accumulate with v_dot2_f32_f16, partial k-quarter sums reduced through LDS.
#define SMEM_BYTES 140288  // 131072 wlds + 1024 hpk + 8192 red

__device__ __forceinline__ float fdot2(uint32_t w, uint32_t h, float acc) {
#if __has_builtin(__builtin_amdgcn_fdot2)
  return __builtin_amdgcn_fdot2(__builtin_bit_cast(f16x2, w),
                                __builtin_bit_cast(f16x2, h), acc, false);
#else
  asm("v_dot2_f32_f16 %0, %1, %2, %0" : "+v"(acc) : "v"(w), "v"(h));
  return acc;
#endif
}

__global__ __launch_bounds__(1024, 4) void rnn_scan(
    const float* __restrict__ Wh, const float* __restrict__ bh,
    const float* __restrict__ h0, float* __restrict__ out) {
  extern __shared__ unsigned char smem[];
  uint32_t* wlds = reinterpret_cast<uint32_t*>(smem);            // [1024*32]
  uint32_t* hpk  = reinterpret_cast<uint32_t*>(smem + 131072);   // [256]
  float*    red  = reinterpret_cast<float*>(smem + 132096);      // [4][512]

  const int r   = blockIdx.x;
  const int tid = threadIdx.x;
  const int j2  = tid & 255;   // column pair index: cols 2*j2, 2*j2+1
  const int kq  = tid >> 8;    // k-quarter: k in [kq*128, kq*128+128)
  const int c0  = j2 * 2;
  const int kbase = kq * 128;
  const int sw  = (tid & 7) << 2;  // LDS bank swizzle (chunk-preserving XOR)

  // Load + pack Wh. pk pairs (k, k+1) for one column -> matches h pk pairs.
  uint32_t wreg[96];
#pragma unroll
  for (int p = 0; p < 64; ++p) {
    const int k = kbase + 2 * p;
    const float2 lo = *reinterpret_cast<const float2*>(Wh + (size_t)k * HH + c0);
    const float2 hi = *reinterpret_cast<const float2*>(Wh + (size_t)(k + 1) * HH + c0);
    f16x2 p0 = {(f16)lo.x, (f16)hi.x};
    f16x2 p1 = {(f16)lo.y, (f16)hi.y};
    const uint32_t u0 = __builtin_bit_cast(uint32_t, p0);
    const uint32_t u1 = __builtin_bit_cast(uint32_t, p1);
    if (p < 48) {
      wreg[2 * p]     = u0;
      wreg[2 * p + 1] = u1;
    } else {
      const int l0 = 2 * (p - 48);
      wlds[tid * 32 + (l0 ^ sw)]       = u0;
      wlds[tid * 32 + ((l0 + 1) ^ sw)] = u1;
    }
  }
  const float bh_r = (tid < HH) ? bh[tid] : 0.f;
  if (tid < 256) {
    f16x2 hp = {(f16)h0[(size_t)r * HH + 2 * tid], (f16)h0[(size_t)r * HH + 2 * tid + 1]};
    hpk[tid] = __builtin_bit_cast(uint32_t, hp);
  }
  __syncthreads();

  const int hbase = kq * 64;
  float* orow = out + (size_t)r * HH;
  for (int t = 0; t < LL; ++t) {
    // xp prefetch (in-place: phase 1 left xp at this address). Masked index
    // keeps the load unconditional + in-bounds; upper waves read a dup line.
    const float xpv = orow[(size_t)t * (BB * HH) + (tid & 511)];
    float a0 = 0.f, a1 = 0.f;
    const uint32_t* hp = hpk + hbase;
#pragma unroll
    for (int u = 0; u < 12; ++u) {  // register-resident 48 k-pairs
      const uint4 hv = *reinterpret_cast<const uint4*>(hp + 4 * u);
      a0 = fdot2(wreg[8 * u + 0], hv.x, a0); a1 = fdot2(wreg[8 * u + 1], hv.x, a1);
      a0 = fdot2(wreg[8 * u + 2], hv.y, a0); a1 = fdot2(wreg[8 * u + 3], hv.y, a1);
      a0 = fdot2(wreg[8 * u + 4], hv.z, a0); a1 = fdot2(wreg[8 * u + 5], hv.z, a1);
      a0 = fdot2(wreg[8 * u + 6], hv.w, a0); a1 = fdot2(wreg[8 * u + 7], hv.w, a1);
    }
#pragma unroll
    for (int u = 0; u < 8; ++u) {  // LDS-resident 16 k-pairs
      const uint4 wv = *reinterpret_cast<const uint4*>(wlds + tid * 32 + ((4 * u) ^ sw));
      const uint2 hv = *reinterpret_cast<const uint2*>(hp + 48 + 2 * u);
      a0 = fdot2(wv.x, hv.x, a0); a1 = fdot2(wv.y, hv.x, a1);
      a0 = fdot2(wv.z, hv.y, a0); a1 = fdot2(wv.w, hv.y, a1);
    }
    *reinterpret_cast<float2*>(red + kq * HH + c0) = make_float2(a0, a1);
    __syncthreads();
    if (tid < HH) {
      const float s = red[tid] + red[HH + tid] + red[2 * HH + tid] + red[3 * HH + tid] +
                      xpv + bh_r;
      const float h = tanhf(s);
      orow[(size_t)t * (BB * HH) + tid] = h;           // overwrite xp in place
      const float hn = __shfl_down(h, 1, 64);
      if (!(tid & 1)) {
        f16x2 hp2 = {(f16)h, (f16)hn};
        hpk[tid >> 1] = __builtin_bit_cast(uint32_t, hp2);
      }
    }
    __syncthreads();
  }
}

extern "C" void kernel_launch(void* const* d_in, const int* in_sizes, int n_in,
                              void* d_out, int out_size, void* d_ws, size_t ws_size,
                              hipStream_t stream) {
  const float* x  = (const float*)d_in[0];
  const float* h0 = (const float*)d_in[1];
  const float* Wx = (const float*)d_in[2];
  const float* bx = (const float*)d_in[3];
  const float* Wh = (const float*)d_in[4];
  const float* bh = (const float*)d_in[5];
  float* out = (float*)d_out;

  (void)in_sizes; (void)n_in; (void)out_size; (void)d_ws; (void)ws_size;

  hipFuncSetAttribute(reinterpret_cast<const void*>(rnn_scan),
                      hipFuncAttributeMaxDynamicSharedMemorySize, SMEM_BYTES);

  xproj_gemm<<<dim3(LL, HH / 128), 256, 0, stream>>>(x, Wx, bx, out);
  rnn_scan<<<dim3(BB), 1024, SMEM_BYTES, stream>>>(Wh, bh, h0, out);
}